// Round 5
// baseline (387.761 us; speedup 1.0000x reference)
//
#include <hip/hip_runtime.h>
#include <math.h>

#define D 4096
#define WPB 8      // waves per workgroup (512 threads), one 16 KiB LDS slice each
#define NBLK 256   // persistent: exactly one 128 KiB-LDS workgroup per CU

// In-register FWHT over the 6 bits of the register index (64 values/thread).
__device__ __forceinline__ void fwht64(float* v) {
#pragma unroll
    for (int h = 1; h < 64; h <<= 1) {
#pragma unroll
        for (int i = 0; i < 64; i += 2 * h) {
#pragma unroll
            for (int j = i; j < i + h; ++j) {
                const float a = v[j];
                const float b = v[j + h];
                v[j]     = a + b;
                v[j + h] = a - b;
            }
        }
    }
}

// Precompute g = g_mu + softplus(g_rho)*eps, pre-permuted into layout-B order:
// gq[l*64 + k] = g[e(k,l)], e = (l&3) | (k<<2) | ((l>>2)<<8)
__global__ void whvi_prep(const float* __restrict__ g_mu,
                          const float* __restrict__ g_rho,
                          const float* __restrict__ eps,
                          float* __restrict__ gq) {
    const int i = blockIdx.x * 64 + threadIdx.x;   // i = l*64 + k
    const int l = i >> 6, k = i & 63;
    const int e = (l & 3) | (k << 2) | ((l >> 2) << 8);
    const float r  = g_rho[e];
    const float sp = (r > 20.f) ? r : log1pf(expf(r));   // stable softplus
    gq[i] = g_mu[e] + sp * eps[e];
}

// PERSISTENT version. Evidence from rounds 0-4:
//  - wave throughput pinned at ~80-90 waves/us regardless of WG size / static
//    caps (r0: 91/us, r4: 77/us) -> front-end dispatch bound, CUs ~70% drained.
//  - barrier-coupled multi-wave WGs lengthen per-row lifetime (r4: 107 vs 90us).
// Fix: 256 WGs x 8 waves, one WG per CU (128 KiB LDS), each wave grid-strides
// over rows with a private 16 KiB LDS slice. No __syncthreads() at all:
// transposes are wave-local; explicit `s_waitcnt lgkmcnt(0)` + "memory"
// clobber orders DS write->read (DS ops complete before the fence passes, so
// cross-lane reads are safe without inter-wave sync; early-exit is safe too).
// Next row's x is prefetched into registers at the top of the row body so HBM
// latency hides under ~8k cycles of FWHT/LDS work.
//
// VGPR LESSON (rounds 1-2): the v[64]+prefetch working set needs ~200 VGPRs.
// Backend budget = 512 / min-waves-per-EU. __launch_bounds__(512, 2) => budget
// 256, no spill. Spill canary: WRITE_SIZE must be exactly 131072 KB.
//
// Layout A: lane l, reg r holds element e = (r&3) | (l<<2) | ((r>>2)<<8)
// Layout B: lane l, reg k holds element e = (l&3) | (k<<2) | ((l>>2)<<8)
// regFWHT(A) -> transpose -> regFWHT(B) covers all 12 bits. LDS xor-swizzle
// sigma(e)=e^((e>>6)&0x1C): b128 writes minimal-phase, b32 reads <=2-way (free).
__global__ void __launch_bounds__(WPB * 64, 2) whvi_main(
    const float* __restrict__ x,  const float* __restrict__ s1,
    const float* __restrict__ s2, const float* __restrict__ gq,
    const float* __restrict__ g_mu, const float* __restrict__ g_rho,
    const float* __restrict__ eps, float* __restrict__ out, int rows) {
    __shared__ alignas(16) float lds_all[WPB * D];   // 128 KiB -> 1 WG/CU, 8 waves/CU
    const int tid = threadIdx.x;
    const int w   = tid >> 6;                        // wave id in WG
    const int l   = tid & 63;                        // lane id
    float* lds = lds_all + (w << 12);                // private 16 KiB slice
    const int gw = blockIdx.x * WPB + w;             // global wave id
    const int nw = gridDim.x * WPB;                  // total waves (2048)
    const int xb = (l & 3) | ((l >> 2) << 8);        // layout-B read base
    const int mk = (l >> 2) & 7;                     // swizzle mask

    long long row = gw;
    if (row >= rows) return;                         // no barriers -> safe exit

    // ---- prologue: issue first row's x prefetch (layout A, dwordx4) ----
    float4 xn[16];
    {
        const float* xr = x + row * (long long)D;
#pragma unroll
        for (int q = 0; q < 16; ++q)
            xn[q] = *reinterpret_cast<const float4*>(xr + (l << 2) + (q << 8));
    }

    while (row < rows) {
        const long long next = row + nw;
        float v[64];

        // ---- consume prefetched x, multiply by s2 (L1-resident) ----
#pragma unroll
        for (int q = 0; q < 16; ++q) {
            const float4 sv = *reinterpret_cast<const float4*>(s2 + (l << 2) + (q << 8));
            v[4 * q + 0] = xn[q].x * sv.x;
            v[4 * q + 1] = xn[q].y * sv.y;
            v[4 * q + 2] = xn[q].z * sv.z;
            v[4 * q + 3] = xn[q].w * sv.w;
        }
        // ---- issue next row's x prefetch; lands during this row's compute ----
        if (next < rows) {
            const float* xr2 = x + next * (long long)D;
#pragma unroll
            for (int q = 0; q < 16; ++q)
                xn[q] = *reinterpret_cast<const float4*>(xr2 + (l << 2) + (q << 8));
        }

        fwht64(v);                   // FWHT-1a: e-bits {0,1,8,9,10,11}

        // ---- transpose 1: write layout A (b128, swizzled) ----
#pragma unroll
        for (int q = 0; q < 16; ++q) {
            const int addr = ((l ^ (q & 7)) << 2) + (q << 8);
            *reinterpret_cast<float4*>(&lds[addr]) =
                make_float4(v[4 * q], v[4 * q + 1], v[4 * q + 2], v[4 * q + 3]);
        }
        asm volatile("s_waitcnt lgkmcnt(0)" ::: "memory");   // writes visible
#pragma unroll
        for (int k = 0; k < 64; ++k)                         // read layout B (b32)
            v[k] = lds[xb + ((k ^ mk) << 2)];

        fwht64(v);                   // FWHT-1b: e-bits {2..7}  (FWHT #1 done)

        // ---- multiply by g (pre-permuted, L1-resident) ----
        if (gq) {
#pragma unroll
            for (int m = 0; m < 16; ++m) {
                const float4 gv = *reinterpret_cast<const float4*>(gq + l * 64 + 4 * m);
                v[4 * m + 0] *= gv.x;
                v[4 * m + 1] *= gv.y;
                v[4 * m + 2] *= gv.z;
                v[4 * m + 3] *= gv.w;
            }
        } else {  // fallback if d_ws too small
#pragma unroll
            for (int k = 0; k < 64; ++k) {
                const int e = (l & 3) | (k << 2) | ((l >> 2) << 8);
                const float r  = g_rho[e];
                const float sp = (r > 20.f) ? r : log1pf(expf(r));
                v[k] *= g_mu[e] + sp * eps[e];
            }
        }

        fwht64(v);                   // FWHT-2a: e-bits {2..7}

        // ---- transpose 2: write layout B (b32), read layout A (b128) ----
        asm volatile("s_waitcnt lgkmcnt(0)" ::: "memory");   // T1 reads drained (WAR)
#pragma unroll
        for (int k = 0; k < 64; ++k)
            lds[xb + ((k ^ mk) << 2)] = v[k];
        asm volatile("s_waitcnt lgkmcnt(0)" ::: "memory");   // writes visible
#pragma unroll
        for (int q = 0; q < 16; ++q) {
            const int addr = ((l ^ (q & 7)) << 2) + (q << 8);
            const float4 t = *reinterpret_cast<const float4*>(&lds[addr]);
            v[4 * q + 0] = t.x;
            v[4 * q + 1] = t.y;
            v[4 * q + 2] = t.z;
            v[4 * q + 3] = t.w;
        }
        asm volatile("s_waitcnt lgkmcnt(0)" ::: "memory");   // reads drained before next iter (WAR)

        fwht64(v);                   // FWHT-2b: e-bits {0,1,8,9,10,11}

        // ---- multiply by s1, store (coalesced dwordx4) ----
        float* outr = out + row * (long long)D;
#pragma unroll
        for (int q = 0; q < 16; ++q) {
            const float4 sv = *reinterpret_cast<const float4*>(s1 + (l << 2) + (q << 8));
            float4 o;
            o.x = v[4 * q + 0] * sv.x;
            o.y = v[4 * q + 1] * sv.y;
            o.z = v[4 * q + 2] * sv.z;
            o.w = v[4 * q + 3] * sv.w;
            *reinterpret_cast<float4*>(outr + (l << 2) + (q << 8)) = o;
        }

        row = next;
    }
}

extern "C" void kernel_launch(void* const* d_in, const int* in_sizes, int n_in,
                              void* d_out, int out_size, void* d_ws, size_t ws_size,
                              hipStream_t stream) {
    const float* x     = (const float*)d_in[0];
    const float* s1    = (const float*)d_in[1];
    const float* s2    = (const float*)d_in[2];
    const float* g_mu  = (const float*)d_in[3];
    const float* g_rho = (const float*)d_in[4];
    const float* eps   = (const float*)d_in[5];
    float* out = (float*)d_out;
    const int rows = in_sizes[0] / D;

    float* gq = nullptr;
    if (ws_size >= (size_t)D * sizeof(float)) {
        gq = (float*)d_ws;
        whvi_prep<<<D / 64, 64, 0, stream>>>(g_mu, g_rho, eps, gq);
    }
    whvi_main<<<NBLK, WPB * 64, 0, stream>>>(x, s1, s2, gq, g_mu, g_rho, eps, out, rows);
}

// Round 7
// 294.849 us; speedup vs baseline: 1.3151x; 1.3151x over previous
//
#include <hip/hip_runtime.h>
#include <math.h>

#define D 4096
#define WPB 4      // waves per workgroup (256 threads); private 16 KiB LDS slice each
#define NBLK 512   // persistent: 2 WGs per CU (2 x 64 KiB LDS = 128 <= 160 KiB)

// In-register FWHT over the 6 bits of the register index (64 values/thread).
__device__ __forceinline__ void fwht64(float* v) {
#pragma unroll
    for (int h = 1; h < 64; h <<= 1) {
#pragma unroll
        for (int i = 0; i < 64; i += 2 * h) {
#pragma unroll
            for (int j = i; j < i + h; ++j) {
                const float a = v[j];
                const float b = v[j + h];
                v[j]     = a + b;
                v[j + h] = a - b;
            }
        }
    }
}

// Precompute g = g_mu + softplus(g_rho)*eps, pre-permuted into layout-B order:
// gq[l*64 + k] = g[e(k,l)], e = (l&3) | (k<<2) | ((l>>2)<<8)
__global__ void whvi_prep(const float* __restrict__ g_mu,
                          const float* __restrict__ g_rho,
                          const float* __restrict__ eps,
                          float* __restrict__ gq) {
    const int i = blockIdx.x * 64 + threadIdx.x;   // i = l*64 + k
    const int l = i >> 6, k = i & 63;
    const int e = (l & 3) | (k << 2) | ((l >> 2) << 8);
    const float r  = g_rho[e];
    const float sp = (r > 20.f) ? r : log1pf(expf(r));   // stable softplus
    gq[i] = g_mu[e] + sp * eps[e];
}

// PERSISTENT kernel, r4-proven compile shape.
//
// COMPILE-SHAPE LEDGER (hard-won, do not deviate):
//   single-arg __launch_bounds__(256) + 64 KiB static LDS  -> VGPR 156, NO spill (r4)
//   single-arg __launch_bounds__(64)  + 16 KiB             -> VGPR 152, NO spill (r0)
//   (64,4) -> 64 VGPR spill | (512,2) -> 128 VGPR spill (2nd arg acts as
//   min-WGs/CU here!) | no bounds (flat-WG 1024) -> 64 VGPR spill.
//   Register prefetch array xn[16] (+64 VGPR) spills even at budget 256 (r5).
//   Spill canary: WRITE_SIZE must be exactly 131072 KB.
//
// Structure: 512 WGs x 4 waves, all resident (2 WGs/CU) for the whole kernel;
// each wave grid-strides over rows (4 rows/wave) with a PRIVATE 16 KiB LDS
// slice. No __syncthreads() anywhere: transposes are wave-local, ordered by
// `s_waitcnt lgkmcnt(0)` + "memory" clobber (structure proven correct in r5).
// This removes the WG churn that kept r0/r4 at ~3 resident waves/CU
// (r0: 91 WG/us launch-bound; r4: 19 WG/us slot-refill-bound).
//
// Layout A: lane l, reg r holds element e = (r&3) | (l<<2) | ((r>>2)<<8)
// Layout B: lane l, reg k holds element e = (l&3) | (k<<2) | ((l>>2)<<8)
// regFWHT(A) -> transpose -> regFWHT(B) covers all 12 bits. LDS xor-swizzle
// sigma(e)=e^((e>>6)&0x1C): b128 writes minimal-phase, b32 reads <=2-way (free).
__global__ void __launch_bounds__(WPB * 64) whvi_main(
    const float* __restrict__ x,  const float* __restrict__ s1,
    const float* __restrict__ s2, const float* __restrict__ gq,
    const float* __restrict__ g_mu, const float* __restrict__ g_rho,
    const float* __restrict__ eps, float* __restrict__ out, int rows) {
    __shared__ alignas(16) float lds_all[WPB * D];   // 64 KiB
    const int tid = threadIdx.x;
    const int w   = tid >> 6;                        // wave id in WG
    const int l   = tid & 63;                        // lane id
    float* lds = lds_all + (w << 12);                // private 16 KiB slice
    const int gw = blockIdx.x * WPB + w;             // global wave id
    const int nw = NBLK * WPB;                       // total waves (2048)
    const int xb = (l & 3) | ((l >> 2) << 8);        // layout-B read base
    const int mk = (l >> 2) & 7;                     // swizzle mask

#pragma clang loop unroll(disable)
    for (long long row = gw; row < rows; row += nw) {
        const float* xr = x + row * (long long)D;
        float v[64];

        // ---- load x*s2, layout A (coalesced dwordx4) ----
#pragma unroll
        for (int q = 0; q < 16; ++q) {
            const int base = (l << 2) + (q << 8);
            const float4 xv = *reinterpret_cast<const float4*>(xr + base);
            const float4 sv = *reinterpret_cast<const float4*>(s2 + base);
            v[4 * q + 0] = xv.x * sv.x;
            v[4 * q + 1] = xv.y * sv.y;
            v[4 * q + 2] = xv.z * sv.z;
            v[4 * q + 3] = xv.w * sv.w;
        }

        fwht64(v);                   // FWHT-1a: e-bits {0,1,8,9,10,11}

        // ---- transpose 1: write layout A (b128, swizzled), read layout B (b32) ----
#pragma unroll
        for (int q = 0; q < 16; ++q) {
            const int addr = ((l ^ (q & 7)) << 2) + (q << 8);
            *reinterpret_cast<float4*>(&lds[addr]) =
                make_float4(v[4 * q], v[4 * q + 1], v[4 * q + 2], v[4 * q + 3]);
        }
        asm volatile("s_waitcnt lgkmcnt(0)" ::: "memory");   // writes visible (wave-local)
#pragma unroll
        for (int k = 0; k < 64; ++k)
            v[k] = lds[xb + ((k ^ mk) << 2)];

        fwht64(v);                   // FWHT-1b: e-bits {2..7}  (FWHT #1 done)

        // ---- multiply by g (pre-permuted, L1-resident) ----
        if (gq) {
#pragma unroll
            for (int m = 0; m < 16; ++m) {
                const float4 gv = *reinterpret_cast<const float4*>(gq + l * 64 + 4 * m);
                v[4 * m + 0] *= gv.x;
                v[4 * m + 1] *= gv.y;
                v[4 * m + 2] *= gv.z;
                v[4 * m + 3] *= gv.w;
            }
        } else {  // fallback if d_ws too small
#pragma unroll
            for (int k = 0; k < 64; ++k) {
                const int e = (l & 3) | (k << 2) | ((l >> 2) << 8);
                const float r  = g_rho[e];
                const float sp = (r > 20.f) ? r : log1pf(expf(r));
                v[k] *= g_mu[e] + sp * eps[e];
            }
        }

        fwht64(v);                   // FWHT-2a: e-bits {2..7}

        // ---- transpose 2: write layout B (b32), read layout A (b128) ----
        asm volatile("s_waitcnt lgkmcnt(0)" ::: "memory");   // T1 b32 reads drained (WAR)
#pragma unroll
        for (int k = 0; k < 64; ++k)
            lds[xb + ((k ^ mk) << 2)] = v[k];
        asm volatile("s_waitcnt lgkmcnt(0)" ::: "memory");   // writes visible
#pragma unroll
        for (int q = 0; q < 16; ++q) {
            const int addr = ((l ^ (q & 7)) << 2) + (q << 8);
            const float4 t = *reinterpret_cast<const float4*>(&lds[addr]);
            v[4 * q + 0] = t.x;
            v[4 * q + 1] = t.y;
            v[4 * q + 2] = t.z;
            v[4 * q + 3] = t.w;
        }
        asm volatile("s_waitcnt lgkmcnt(0)" ::: "memory");   // reads drained before next row (WAR)

        fwht64(v);                   // FWHT-2b: e-bits {0,1,8,9,10,11}

        // ---- multiply by s1, store (coalesced dwordx4) ----
        float* outr = out + row * (long long)D;
#pragma unroll
        for (int q = 0; q < 16; ++q) {
            const int base = (l << 2) + (q << 8);
            const float4 sv = *reinterpret_cast<const float4*>(s1 + base);
            float4 o;
            o.x = v[4 * q + 0] * sv.x;
            o.y = v[4 * q + 1] * sv.y;
            o.z = v[4 * q + 2] * sv.z;
            o.w = v[4 * q + 3] * sv.w;
            *reinterpret_cast<float4*>(outr + base) = o;
        }
    }
}

extern "C" void kernel_launch(void* const* d_in, const int* in_sizes, int n_in,
                              void* d_out, int out_size, void* d_ws, size_t ws_size,
                              hipStream_t stream) {
    const float* x     = (const float*)d_in[0];
    const float* s1    = (const float*)d_in[1];
    const float* s2    = (const float*)d_in[2];
    const float* g_mu  = (const float*)d_in[3];
    const float* g_rho = (const float*)d_in[4];
    const float* eps   = (const float*)d_in[5];
    float* out = (float*)d_out;
    const int rows = in_sizes[0] / D;

    float* gq = nullptr;
    if (ws_size >= (size_t)D * sizeof(float)) {
        gq = (float*)d_ws;
        whvi_prep<<<D / 64, 64, 0, stream>>>(g_mu, g_rho, eps, gq);
    }
    whvi_main<<<NBLK, WPB * 64, 0, stream>>>(x, s1, s2, gq, g_mu, g_rho, eps, out, rows);
}